// Round 13
// baseline (368.489 us; speedup 1.0000x reference)
//
#include <hip/hip_runtime.h>

#define TT 4
#define BB 2
#define CC 128
#define DD 8
#define HHH 32
#define WWW 32
#define PP (DD*HHH*WWW)        // 8192
#define TSTRIDE (BB*CC*PP)     // 2097152
#define NWIN 8
#define SSS 1024
#define NHEAD 8
#define HDIM 16
#define THETA 0.7f
#define VTH 1.0f
#define NPERC (TT*BB*PP)       // 65536
#define EPSf 1e-5f

typedef unsigned short ushortT;
typedef unsigned char ucharT;
typedef unsigned int uintT;
typedef _Float16 half_t;
typedef _Float16 f16x8 __attribute__((ext_vector_type(8)));
typedef float    f32x16 __attribute__((ext_vector_type(16)));

typedef const __attribute__((address_space(1))) void* as1_cvp;
typedef __attribute__((address_space(3))) void* as3_vp;

// ---------------- mega-prep: wfrag + w1frags + xsplit in ONE launch ---------
__global__ __launch_bounds__(256) void prep_all(const float* __restrict__ qw,
                                                const float* __restrict__ Wk,
                                                const float* __restrict__ Wp,
                                                const float* __restrict__ x,
                                                half_t* __restrict__ wfrag,
                                                half_t* __restrict__ fragk,
                                                half_t* __restrict__ fragp,
                                                half_t* __restrict__ xsp) {
    int bid = blockIdx.x;
    int tid = threadIdx.x;
    if (bid < 216) {
        int id = bid*256 + tid;              // 55296 = 8*27*4*64
        if (id >= 8*27*4*64) return;
        int lane = id & 63;
        int r = id >> 6;
        int m = r & 3; r >>= 2;
        int t = r % 27;
        int kb = r / 27;
        int o   = m*32 + (lane & 31);
        int ic0 = kb*16 + (lane>>5)*8;
        size_t base = ((size_t)(id>>6))*2*64*8 + (size_t)lane*8;
        #pragma unroll
        for (int j=0;j<8;j++){
            const float* wp = qw + ((size_t)o*CC + ic0 + j)*27;
            float v = wp[t];
            if (t == 13) {                   // t uniform per wave: no divergence
                float kd = 0.f;
                #pragma unroll
                for (int tt=0; tt<9; tt++) kd += wp[tt] + wp[18+tt];
                v -= THETA*kd;
            }
            half_t h = (half_t)v;
            half_t l = (half_t)(v - (float)h);
            wfrag[base + 0*64*8 + j] = h;
            wfrag[base + 1*64*8 + j] = l;
        }
    } else if (bid < 232) {
        int id = (bid-216)*256 + tid;        // 4096
        if (id >= 4096) return;
        const float* W    = (id < 2048) ? Wk : Wp;
        half_t*      frag = (id < 2048) ? fragk : fragp;
        int i2 = id & 2047;
        int lane = i2 & 63;
        int r = i2 >> 6;
        int m = r & 3;
        int kb = r >> 2;
        int o   = m*32 + (lane & 31);
        int ic0 = kb*16 + (lane>>5)*8;
        size_t base = ((size_t)(kb*4+m))*2*64*8 + (size_t)lane*8;
        #pragma unroll
        for (int j=0;j<8;j++){
            float v = W[(size_t)o*CC + ic0 + j];
            half_t h = (half_t)v;
            half_t l = (half_t)(v - (float)h);
            frag[base + 0*64*8 + j] = h;
            frag[base + 1*64*8 + j] = l;
        }
    } else {
        int id = (bid-232)*256 + tid;        // 8*16*8*34*34 = 1,183,744
        if (id >= 8*16*8*34*34) return;
        int wt = id % 34; int r = id/34;
        int hp = r % 34;  r /= 34;
        int dz = r % 8;   r /= 8;
        int icg = r & 15; int tb = r >> 4;
        bool inb = (hp>=1) & (hp<=32) & (wt>=1) & (wt<=32);
        half_t h8[8], l8[8];
        #pragma unroll
        for (int j=0;j<8;j++){
            float v = 0.f;
            if (inb)
                v = x[((size_t)(tb*CC + icg*8+j))*PP + (size_t)dz*1024 + (hp-1)*32 + (wt-1)];
            half_t h = (half_t)v;
            half_t l = (half_t)(v - (float)h);
            h8[j]=h; l8[j]=l;
        }
        #pragma unroll
        for (int sp=0; sp<2; sp++){
            size_t gu = (((((size_t)tb*2 + sp)*16 + icg)*8 + dz)*34 + hp)*34 + wt;
            half_t* dst = xsp + gu*8;
            const half_t* src = (sp==0)?h8:l8;
            #pragma unroll
            for (int j=0;j<8;j++) dst[j] = src[j];
        }
    }
}

// ---------------- conv (full-K) + FUSED k-gemm phase 2 ----------------------
__global__ __launch_bounds__(512,2) void conv_mfma4(const half_t* __restrict__ xsp,
                                                    const half_t* __restrict__ wfrag,
                                                    const half_t* __restrict__ wk,
                                                    float* __restrict__ y,
                                                    float* __restrict__ yk) {
    extern __shared__ half_t slab[];         // 2 x 3264 units x 16B
    int tid  = threadIdx.x;
    int wid  = tid >> 6;
    int lane = tid & 63;
    int ln   = lane & 31;
    int half_ = lane >> 5;
    int hg = blockIdx.x;                     // 0..7
    int dp = blockIdx.y;                     // 0..3
    int tb = blockIdx.z;                     // 0..7
    int H0 = hg*4, d0 = dp*2;
    int r  = wid & 3;                        // h-row within block
    int mh = wid >> 2;                       // m-half: owns m = mh*2 + {0,1}

    auto STAGE = [&](int kb, int bsel) {
        half_t* bufp = slab + (size_t)bsel*(3264*8);
        #pragma unroll 1
        for (int k2=0; k2<7; k2++) {
            int u = tid + (k2<<9);
            if (u < 3264) {
                int sp  = (u >= 1632) ? 1 : 0;
                int r1  = u - sp*1632;
                int icg = (r1 >= 816) ? 1 : 0;
                int p2  = r1 - icg*816;
                int dzs = p2/204; int r3 = p2 - dzs*204;
                int hp  = r3/34;  int wt = r3 - hp*34;
                int dd  = d0 - 1 + dzs;
                const half_t* src = ((unsigned)dd < 8u)
                    ? &xsp[((((((size_t)tb*2 + sp)*16 + (kb*2+icg))*8 + dd)*34 + (H0+hp))*34 + wt)*8]
                    : &xsp[(size_t)ln*8];    // hp=0 halo row of xsp: guaranteed zeros
                __builtin_amdgcn_global_load_lds((as1_cvp)src,
                    (as3_vp)(bufp + (size_t)u*8), 16, 0, 0);
            }
        }
    };

    f32x16 accA[2][2], accB[2][2];           // [dt][mm]; A: kb0-3, B: kb4-7
    #pragma unroll
    for (int dt=0;dt<2;dt++)
        #pragma unroll
        for (int mm=0;mm<2;mm++)
            #pragma unroll
            for (int i=0;i<16;i++){ accA[dt][mm][i]=0.f; accB[dt][mm][i]=0.f; }

    f16x8 ca[2][2];
    #pragma unroll
    for (int mm=0;mm<2;mm++)
        #pragma unroll
        for (int sp=0;sp<2;sp++)
            ca[mm][sp] = *(const f16x8*)&wfrag[((((size_t)0*4 + (mh*2+mm))*2+sp)*64 + lane)*8];

    asm volatile("" ::: "memory");
    STAGE(0,0);
    STAGE(1,1);
    asm volatile("" ::: "memory");

    auto KBODY = [&](int kk, f32x16 (&acc)[2][2]) {
        if (kk == 0) {
            if (wid < 3) asm volatile("s_waitcnt vmcnt(7)" ::: "memory");
            else         asm volatile("s_waitcnt vmcnt(6)" ::: "memory");
        } else {
            asm volatile("s_waitcnt vmcnt(63)" ::: "memory");
        }
        __builtin_amdgcn_s_barrier();        // publish buf[kk&1]
        asm volatile("" ::: "memory");
        const half_t* bufp = slab + (size_t)(kk&1)*(3264*8);

        f16x8 cbC[2][2], cbN[2][2];
        #pragma unroll
        for (int dt=0; dt<2; dt++){
            int unitb = dt*204 + r*34 + ln;
            #pragma unroll
            for (int sp=0; sp<2; sp++)
                cbC[dt][sp] = *(const f16x8*)&bufp[(size_t)((sp*2+half_)*816 + unitb)*8];
        }

        #pragma unroll 1
        for (int t=0; t<27; t++) {
            int t2 = (t<26)? t+1 : 26;
            int dz2=t2/9; int rr2=t2-dz2*9; int dh2=rr2/3; int dw2=rr2-dh2*3;
            #pragma unroll
            for (int dt=0; dt<2; dt++){
                int unitb = (dt + dz2)*204 + (r+dh2)*34 + (ln+dw2);
                #pragma unroll
                for (int sp=0; sp<2; sp++)
                    cbN[dt][sp] = *(const f16x8*)&bufp[(size_t)((sp*2+half_)*816 + unitb)*8];
            }
            f16x8 na[2][2];
            int nt  = (t<26)? t+1 : 0;
            int nkb = (t<26)? kk  : ((kk<7)? kk+1 : kk);
            #pragma unroll
            for (int mm=0;mm<2;mm++)
                #pragma unroll
                for (int sp=0;sp<2;sp++)
                    na[mm][sp] = *(const f16x8*)&wfrag[((((size_t)(nkb*27+nt)*4+(mh*2+mm))*2+sp)*64 + lane)*8];
            #pragma unroll
            for (int dt=0;dt<2;dt++)
                #pragma unroll
                for (int mm=0;mm<2;mm++) acc[dt][mm] = __builtin_amdgcn_mfma_f32_32x32x16_f16(ca[mm][0], cbC[dt][0], acc[dt][mm],0,0,0);
            #pragma unroll
            for (int dt=0;dt<2;dt++)
                #pragma unroll
                for (int mm=0;mm<2;mm++) acc[dt][mm] = __builtin_amdgcn_mfma_f32_32x32x16_f16(ca[mm][0], cbC[dt][1], acc[dt][mm],0,0,0);
            #pragma unroll
            for (int dt=0;dt<2;dt++)
                #pragma unroll
                for (int mm=0;mm<2;mm++) acc[dt][mm] = __builtin_amdgcn_mfma_f32_32x32x16_f16(ca[mm][1], cbC[dt][0], acc[dt][mm],0,0,0);
            #pragma unroll
            for (int dt=0;dt<2;dt++)
                #pragma unroll
                for (int sp=0;sp<2;sp++) cbC[dt][sp] = cbN[dt][sp];
            #pragma unroll
            for (int mm=0;mm<2;mm++)
                #pragma unroll
                for (int sp=0;sp<2;sp++) ca[mm][sp] = na[mm][sp];
        }
        asm volatile("" ::: "memory");
        __builtin_amdgcn_s_barrier();        // all waves done reading buf[kk&1]
        asm volatile("" ::: "memory");
        if (kk < 6) STAGE(kk+2, kk&1);       // refill the buffer just vacated
    };

    #pragma unroll 1
    for (int kk=0; kk<4; kk++) KBODY(kk, accA);
    #pragma unroll 1
    for (int kk=4; kk<8; kk++) KBODY(kk, accB);

    {
        int h = H0 + r;
        #pragma unroll
        for (int dt=0; dt<2; dt++) {
            int d = d0 + dt;
            #pragma unroll
            for (int mm=0; mm<2; mm++) {
                #pragma unroll
                for (int reg=0; reg<16; reg++) {
                    int row = (reg&3) + 8*(reg>>2) + 4*half_;
                    int o = (mh*2+mm)*32 + row;
                    y[((size_t)tb*CC + o)*PP + d*1024 + h*32 + ln]
                        = accA[dt][mm][reg] + accB[dt][mm][reg];
                }
            }
        }
    }

    // ---- phase 2: k-gemm for this block's (d0..d0+1, H0..H0+3, tb) --------
    {
        int d = d0 + (wid >> 2);
        int h = H0 + (wid & 3);
        f32x16 kacc[4];
        #pragma unroll
        for (int m=0;m<4;m++)
            #pragma unroll
            for (int i=0;i<16;i++) kacc[m][i] = 0.f;

        #pragma unroll 2
        for (int kb=0; kb<8; kb++) {
            f16x8 b[2];
            #pragma unroll
            for (int sp=0; sp<2; sp++) {
                size_t gu = (((((size_t)tb*2 + sp)*16 + (kb*2+half_))*8 + d)*34 + (h+1))*34 + (ln+1);
                b[sp] = *(const f16x8*)&xsp[gu*8];
            }
            #pragma unroll
            for (int m=0; m<4; m++) {
                const half_t* wb = wk + ((size_t)(kb*4+m))*2*64*8 + (size_t)lane*8;
                f16x8 a0 = *(const f16x8*)&wb[0*64*8];
                f16x8 a1 = *(const f16x8*)&wb[1*64*8];
                kacc[m] = __builtin_amdgcn_mfma_f32_32x32x16_f16(a0, b[0], kacc[m],0,0,0);
                kacc[m] = __builtin_amdgcn_mfma_f32_32x32x16_f16(a0, b[1], kacc[m],0,0,0);
                kacc[m] = __builtin_amdgcn_mfma_f32_32x32x16_f16(a1, b[0], kacc[m],0,0,0);
            }
        }
        #pragma unroll
        for (int m=0; m<4; m++) {
            #pragma unroll
            for (int reg=0; reg<16; reg++) {
                int row = (reg&3) + 8*(reg>>2) + 4*half_;
                int o = m*32 + row;
                yk[((size_t)tb*CC + o)*PP + d*1024 + h*32 + ln] = kacc[m][reg];
            }
        }
    }
}

// ---------------- p-gemm via f16 MFMA (plain: no stats epilogue) ------------
__global__ __launch_bounds__(256) void pgemm_mfma(const ushortT* __restrict__ spkb,
                                                  const half_t* __restrict__ wp,
                                                  float* __restrict__ y) {
    int tid  = threadIdx.x;
    int wid  = tid >> 6;
    int lane = tid & 63;
    int ln   = lane & 31;
    int half_ = lane >> 5;
    int hg = blockIdx.x, d = blockIdx.y, tb = blockIdx.z;
    int h = hg*4 + wid;
    int p = d*1024 + h*32 + ln;

    f32x16 acc[4];
    #pragma unroll
    for (int m=0;m<4;m++)
        #pragma unroll
        for (int i=0;i<16;i++) acc[m][i] = 0.f;

    #pragma unroll 2
    for (int kb=0; kb<8; kb++) {
        f16x8 b = *(const f16x8*)&spkb[(((size_t)tb*16 + (kb*2+half_))*PP + p)*8];
        #pragma unroll
        for (int m=0; m<4; m++) {
            const half_t* wb = wp + ((size_t)(kb*4+m))*2*64*8 + (size_t)lane*8;
            f16x8 a0 = *(const f16x8*)&wb[0*64*8];
            f16x8 a1 = *(const f16x8*)&wb[1*64*8];
            acc[m] = __builtin_amdgcn_mfma_f32_32x32x16_f16(a0, b, acc[m],0,0,0);
            acc[m] = __builtin_amdgcn_mfma_f32_32x32x16_f16(a1, b, acc[m],0,0,0);
        }
    }
    #pragma unroll
    for (int m=0; m<4; m++) {
        #pragma unroll
        for (int reg=0; reg<16; reg++) {
            int row = (reg&3) + 8*(reg>>2) + 4*half_;
            int o = m*32 + row;
            y[((size_t)tb*CC + o)*PP + p] = acc[m][reg];
        }
    }
}

// ---------------- per-(src,b,win,c) sum & sumsq partials ---------------------
__global__ __launch_bounds__(128) void win_stats(const float* __restrict__ q,
        const float* __restrict__ k, const float* __restrict__ x,
        float* __restrict__ rsum, float* __restrict__ rsq) {
    int blk = blockIdx.x;
    int src = blk >> 11;
    int r   = blk & 2047;
    const float* base = (src==0) ? q : ((src==1) ? k : x);
    int c  = r & 127;
    int wi = (r >> 7) & 7;
    int b  = r >> 10;
    int wd = wi>>2, wh = (wi>>1)&1, ww = wi&1;
    int tid = threadIdx.x;
    float s=0.f, s2=0.f;
    for (int t=0;t<TT;t++){
        const float* p = base + ((size_t)(t*BB+b)*CC + c)*PP;
        for (int si=tid; si<SSS; si+=128){
            int ld = si>>8, lh=(si>>4)&15, lw=si&15;
            float v = p[((wd*4+ld)<<10) + ((wh*16+lh)<<5) + (ww*16+lw)];
            s += v; s2 += v*v;
        }
    }
    __shared__ float ls[128], ls2[128];
    ls[tid]=s; ls2[tid]=s2; __syncthreads();
    for (int off=64;off>0;off>>=1){
        if(tid<off){ ls[tid]+=ls[tid+off]; ls2[tid]+=ls2[tid+off]; }
        __syncthreads();
    }
    if (tid==0){ rsum[blk]=ls[0]; rsq[blk]=ls2[0]; }
}

// ---------------- finalize stats + routing + top-4 in ONE block --------------
__global__ __launch_bounds__(384) void route_fin(const float* __restrict__ rsum,
        const float* __restrict__ rsq,
        const float* __restrict__ qg, const float* __restrict__ qb,
        const float* __restrict__ kg, const float* __restrict__ kb,
        float* __restrict__ stats, int* __restrict__ idxout) {
    __shared__ float qn[16*128], kn[16*128], ar[16*8];
    __shared__ float csum[384], csq[384];
    int tid = threadIdx.x;
    {
        int src = tid >> 7, c = tid & 127;
        float s=0.f, s2=0.f;
        for (int bw=0; bw<16; bw++){
            int idx = src*2048 + bw*128 + c;
            s  += rsum[idx];
            s2 += rsq[idx];
        }
        stats[src*256 + c]       = s;
        stats[src*256 + 128 + c] = s2;
        csum[tid]=s; csq[tid]=s2;
    }
    __syncthreads();
    for (int e=tid; e<16*128; e+=384){
        int c = e&127;
        float qm = csum[c]*(1.f/NPERC);
        float qv = csq[c]*(1.f/NPERC) - qm*qm;
        float qr = rsqrtf(qv + EPSf);
        qn[e] = (rsum[e]*(1.f/(TT*SSS)) - qm)*qr*qg[c] + qb[c];
        float km = csum[128+c]*(1.f/NPERC);
        float kv = csq[128+c]*(1.f/NPERC) - km*km;
        float kr = rsqrtf(kv + EPSf);
        kn[e] = (rsum[2048+e]*(1.f/(TT*SSS)) - km)*kr*kg[c] + kb[c];
    }
    __syncthreads();
    if (tid < 128){
        int b = tid>>6, w=(tid>>3)&7, v=tid&7;
        float s=0.f;
        for (int c=0;c<128;c++) s += qn[(b*8+w)*128+c]*kn[(b*8+v)*128+c];
        ar[(b*8+w)*8+v] = s * 0.25f;
    }
    __syncthreads();
    if (tid < 16){
        const float* row = &ar[tid*8];
        bool used[8] = {false,false,false,false,false,false,false,false};
        for (int j=0;j<4;j++){
            int best=0; float bv=-3.0e38f;
            for (int v=0; v<8; v++){
                if (!used[v] && row[v] > bv){ bv=row[v]; best=v; }
            }
            used[best]=true;
            idxout[tid*4+j]=best;
        }
    }
}

// ---------------- LIF+BN for q,k,v in ONE launch (grid.y = src) -------------
// v13: coalesced-write remap. Block = (b, wd, wh, c); thread covers full 32-w
// rows -> reads stay 128B-contiguous per 8 threads AND spike writes become two
// 128B-contiguous segments per wave (optimal for 256B/wave). Pure per-element
// op: thread remap changes no FP order -> bit-identical spikes.
__global__ __launch_bounds__(256) void lif_bn_win3(const float* __restrict__ qin,
        const float* __restrict__ kin, const float* __restrict__ xin,
        ucharT* __restrict__ qs, ucharT* __restrict__ ks, ucharT* __restrict__ vs,
        const float* __restrict__ stats,
        const float* __restrict__ qg, const float* __restrict__ qb,
        const float* __restrict__ kg, const float* __restrict__ kb,
        const float* __restrict__ vg, const float* __restrict__ vb) {
    int src = blockIdx.y;
    const float* in  = (src==0) ? qin : ((src==1) ? kin : xin);
    ucharT*      spk = (src==0) ? qs  : ((src==1) ? ks  : vs);
    const float* gamma = (src==0) ? qg : ((src==1) ? kg : vg);
    const float* beta  = (src==0) ? qb : ((src==1) ? kb : vb);
    int bid = blockIdx.x;                    // 1024 = b2 x wd2 x wh2 x c128
    int c  = bid & 127;
    int wh = (bid>>7) & 1;
    int wd = (bid>>8) & 1;
    int b  = bid>>9;
    int tid = threadIdx.x;
    float mean = stats[src*256 + c]*(1.f/NPERC);
    float var  = stats[src*256 + 128 + c]*(1.f/NPERC) - mean*mean;
    float sc = rsqrtf(var+EPSf)*gamma[c];
    float sh = beta[c] - mean*sc;

    // per-k geometry (k=0,1): idx = tid + 256k; w4 0..7, lh 0..15, ld 0..3
    int w4_[2], p_[2];
    size_t widx_[2];
    #pragma unroll
    for (int k=0;k<2;k++){
        int idx = tid + (k<<8);
        int w4 = idx & 7;
        int lh = (idx>>3) & 15;
        int ld = idx>>7;
        int w  = w4*4;
        int ww = w>>4;
        int wi = wd*4 + wh*2 + ww;
        int si = (ld<<8) + (lh<<4) + (w&15);
        w4_[k] = w4;
        p_[k]  = ((wd*4+ld)<<10) + ((wh*16+lh)<<5) + w;
        widx_[k] = ((size_t)(b*NWIN+wi)*CC + c)*SSS + si;    // multiple of 4
    }
    size_t ebase = ((size_t)b*CC + c)*PP;

    float v[2][4];
    #pragma unroll
    for (int k=0;k<2;k++)
        #pragma unroll
        for (int i=0;i<4;i++) v[k][i] = 0.f;

    #pragma unroll
    for (int t=0;t<TT;t++){
        size_t toff = (size_t)t*TSTRIDE + ebase;
        #pragma unroll
        for (int k=0;k<2;k++){
            float4 raw = *(const float4*)&in[toff + p_[k]];
            float xs[4] = {raw.x, raw.y, raw.z, raw.w};
            uintT pack = 0;
            #pragma unroll
            for (int i=0;i<4;i++){
                float xn = xs[i]*sc + sh;
                v[k][i] = (v[k][i]+xn)*0.5f;
                float s = (v[k][i]>=VTH)?1.f:0.f;
                pack |= (v[k][i]>=VTH ? 1u : 0u) << (8*i);
                v[k][i] *= (1.f - s);
            }
            *(uintT*)&spk[(size_t)t*TSTRIDE + widx_[k]] = pack;
        }
    }
}

// ---------------- window attention + output LIF -> f16 spike frags ----------
__global__ __launch_bounds__(256) void attn_lif(const ucharT* __restrict__ qspk,
        const ucharT* __restrict__ kspk, const ucharT* __restrict__ vspk,
        const int* __restrict__ idx, ushortT* __restrict__ spkb) {
    int id = blockIdx.x*256 + threadIdx.x;   // [b2][wi8][hh8][s4 256][ddq4] = 131072
    int ddq = id & 3;                        // dd = ddq*4 .. +3
    int s4  = (id>>2) & 255;                 // s = s4*4 .. +3
    int hh  = (id>>10) & 7;
    int wi  = (id>>13) & 7;
    int b   = id>>16;
    int bw  = b*NWIN+wi;
    int s0  = s4*4;
    int dd0 = ddq*4;
    size_t qbase = ((size_t)bw*CC + hh*HDIM + dd0)*SSS + s0;
    size_t sbase[4];
    #pragma unroll
    for (int j=0;j<4;j++){
        int srcw = idx[bw*4+j];
        sbase[j] = ((size_t)(b*NWIN+srcw)*CC + hh*HDIM + dd0)*SSS + s0;
    }
    int wd = wi>>2, wh = (wi>>1)&1, ww = wi&1;
    int d3 = wd*4 + (s0>>8), h3 = wh*16 + ((s0>>4)&15), w3 = ww*16 + (s0&15);
    int p0 = (d3<<10) + (h3<<5) + w3;        // p for si: p0+si (same d3/h3)
    int icg  = hh*2 + (ddq>>1);
    int slot = (ddq&1)*4;

    float v[4] = {0.f,0.f,0.f,0.f};
    float v2[4][4];
    #pragma unroll
    for (int i=0;i<4;i++)
        #pragma unroll
        for (int si=0;si<4;si++) v2[i][si]=0.f;

    #pragma unroll 1
    for (int t=0;t<TT;t++){
        size_t toff = (size_t)t*TSTRIDE;
        uintT km[4] = {0,0,0,0}, vm[4] = {0,0,0,0};
        #pragma unroll
        for (int j=0;j<4;j++){
            const ucharT* kp = kspk+toff+sbase[j];
            const ucharT* vp = vspk+toff+sbase[j];
            #pragma unroll
            for (int i=0; i<4; i++){
                km[i] += *(const uintT*)&kp[(size_t)i*SSS];   // bytes <= 4: no carry
                vm[i] += *(const uintT*)&vp[(size_t)i*SSS];
            }
        }
        const ucharT* qp = qspk+toff+qbase;
        uintT atti = 0;                      // per-byte dot over this dd-quarter
        #pragma unroll
        for (int i=0;i<4;i++){
            uintT q4 = *(const uintT*)&qp[(size_t)i*SSS];     // bytes in {0,1}
            uintT tq = (q4 + 0x7F7F7F7Fu) & 0x80808080u;      // 0x80 where q=1
            uintT mask = tq - (tq >> 7);                      // 0x7F where q=1
            atti += km[i] & mask;            // km bytes <=4 -> fits in 0x7F
        }
        atti += (uintT)__shfl_xor((int)atti, 1);              // quad sum over dd
        atti += (uintT)__shfl_xor((int)atti, 2);              // bytes <=64: exact
        int tb2 = t*BB + b;
        size_t obase = (((size_t)tb2*16 + icg)*PP + p0)*8 + slot;
        #pragma unroll
        for (int si=0; si<4; si++){
            float att = (float)((atti >> (8*si)) & 255u) * 0.25f;
            v[si] = (v[si]+att)*0.5f;
            float sp = (v[si]>=VTH)?1.f:0.f;
            v[si] *= (1.f-sp);
            float spq = sp*0.25f;
            uintT lo=0, hi=0;
            #pragma unroll
            for (int i=0;i<4;i++){
                float ov = spq*(float)((vm[i] >> (8*si)) & 255u);
                v2[i][si] = (v2[i][si]+ov)*0.5f;
                float s2 = (v2[i][si]>=VTH)?1.f:0.f;
                v2[i][si] *= (1.f-s2);
                uintT bs = (s2 != 0.f) ? 0x3C00u : 0u;        // f16 1.0
                if (i<2) lo |= bs << (16*i); else hi |= bs << (16*(i-2));
            }
            uint2 pk; pk.x = lo; pk.y = hi;
            *(uint2*)&spkb[obase + (size_t)si*8] = pk;        // 8B store
        }
    }
}

// ---------------- p-stats: partials over (tb,c) ------------------------------
__global__ __launch_bounds__(256) void pstats_part(const float* __restrict__ xin,
        float* __restrict__ part_sum, float* __restrict__ part_sq) {
    int blk = blockIdx.x;                    // tb*128 + c
    int c = blk & 127, tb = blk >> 7;
    int tid = threadIdx.x;
    const float* p = xin + ((size_t)tb*CC + c)*PP;
    float s=0.f, s2=0.f;
    for (int i=tid; i<PP; i+=256){ float v=p[i]; s+=v; s2+=v*v; }
    __shared__ float ls[256], ls2[256];
    ls[tid]=s; ls2[tid]=s2; __syncthreads();
    for (int off=128; off>0; off>>=1){
        if (tid<off){ ls[tid]+=ls[tid+off]; ls2[tid]+=ls2[tid+off]; }
        __syncthreads();
    }
    if (tid==0){ part_sum[blk]=ls[0]; part_sq[blk]=ls2[0]; }
}

// ---------------- final BN apply (folds the 8-partial finalize; float4) -----
__global__ __launch_bounds__(256) void bn_apply(const float* __restrict__ xin,
        float* __restrict__ yout,
        const float* __restrict__ part_sum, const float* __restrict__ part_sq,
        const float* __restrict__ gamma, const float* __restrict__ beta) {
    size_t i4 = (size_t)blockIdx.x*256 + threadIdx.x;
    if (i4 >= (size_t)TT*BB*CC*PP/4) return;
    size_t i = i4*4;
    int c = (int)((i>>13)&127);
    float s=0.f, s2=0.f;
    #pragma unroll
    for (int tb=0; tb<8; tb++){
        s  += part_sum[tb*128+c];
        s2 += part_sq[tb*128+c];
    }
    float mean = s*(1.f/NPERC);
    float var  = s2*(1.f/NPERC) - mean*mean;
    float sc = rsqrtf(var+EPSf)*gamma[c];
    float sh = beta[c] - mean*sc;
    float4 a = *(const float4*)&xin[i];
    a.x = a.x*sc + sh;
    a.y = a.y*sc + sh;
    a.z = a.z*sc + sh;
    a.w = a.w*sc + sh;
    *(float4*)&yout[i] = a;
}

extern "C" void kernel_launch(void* const* d_in, const int* in_sizes, int n_in,
                              void* d_out, int out_size, void* d_ws, size_t ws_size,
                              hipStream_t stream) {
    const float* x  = (const float*)d_in[0];
    const float* qw = (const float*)d_in[1];
    const float* qg = (const float*)d_in[2];
    const float* qb = (const float*)d_in[3];
    const float* kw = (const float*)d_in[4];
    const float* kg = (const float*)d_in[5];
    const float* kb = (const float*)d_in[6];
    const float* vg = (const float*)d_in[7];
    const float* vb = (const float*)d_in[8];
    const float* pw = (const float*)d_in[9];
    const float* pg = (const float*)d_in[10];
    const float* pb = (const float*)d_in[11];
    float* out = (float*)d_out;
    float* ws  = (float*)d_ws;

    const size_t NEL = (size_t)TT*TSTRIDE;   // 8,388,608 floats
    // ---- workspace layout (v13 = R12 best + lif write-coalesce) -------------
    float* qconv = ws;
    half_t* xsp  = (half_t*)(ws + 2*NEL);
    const size_t KCONV_OFF = 2*NEL + 10747904;        // past xsp end (2NEL+9469952)
    float* kconv = ws + KCONV_OFF;
    float* wf_base = ws + KCONV_OFF + NEL;            // weight area
    half_t* wfrag  = (half_t*)wf_base;                // 884736 halves (442368 f)
    half_t* wkfrag = (half_t*)(wf_base + 442368);     // 32768 halves (16384 f)
    half_t* wpfrag = (half_t*)(wf_base + 442368 + 16384 + 442368); // 32768 halves
    float* stats = ws + 5*NEL;
    float* rsum = stats + 1024;              // 6144
    float* rsq  = rsum + 6144;               // 6144
    float* ppart_sum = rsq + 6144;           // 1024
    float* ppart_sq  = ppart_sum + 1024;     // 1024
    int*   idxp = (int*)(ppart_sq + 1024);   // 64 ints

    ucharT* qspk = (ucharT*)(ws + 2*NEL);             // after xsp dead
    ucharT* kspk = (ucharT*)(ws + 2*NEL) + 8388608;
    ucharT* vspk = (ucharT*)(ws + 2*NEL) + 16777216;
    ushortT* spkb  = (ushortT*)ws;                    // qconv dead after lif
    float*  pconv  = ws + KCONV_OFF;                  // kconv dead after lif

    prep_all<<<4856,256,0,stream>>>(qw, kw, pw, x, wfrag, wkfrag, wpfrag, xsp);
    {
        // 104,448 B dynamic LDS (> 64 KB): opt in once (host-side, capture-safe)
        static bool attr_set = false;
        const int shmem = 2*3264*8*(int)sizeof(half_t);
        if (!attr_set) {
            hipFuncSetAttribute((const void*)conv_mfma4,
                                hipFuncAttributeMaxDynamicSharedMemorySize, shmem);
            attr_set = true;
        }
        dim3 cg(8,4,8);
        conv_mfma4<<<cg,512,shmem,stream>>>(xsp, wfrag, wkfrag, qconv, kconv);
    }
    win_stats<<<6144,128,0,stream>>>(qconv, kconv, x, rsum, rsq);
    route_fin<<<1,384,0,stream>>>(rsum, rsq, qg,qb,kg,kb, stats, idxp);
    {
        dim3 lg(1024,3);
        lif_bn_win3<<<lg,256,0,stream>>>(qconv,kconv,x,
                                         qspk,kspk,vspk,
                                         stats, qg,qb,kg,kb,vg,vb);
    }
    attn_lif<<<512,256,0,stream>>>(qspk,kspk,vspk,idxp,spkb);
    {
        dim3 gg(8,8,8);
        pgemm_mfma<<<gg,256,0,stream>>>(spkb, wpfrag, pconv);
    }
    pstats_part<<<1024,256,0,stream>>>(pconv, ppart_sum, ppart_sq);
    bn_apply<<<8192,256,0,stream>>>(pconv, out, ppart_sum, ppart_sq, pg, pb);
}

// Round 14
// 361.831 us; speedup vs baseline: 1.0184x; 1.0184x over previous
//
#include <hip/hip_runtime.h>

#define TT 4
#define BB 2
#define CC 128
#define DD 8
#define HHH 32
#define WWW 32
#define PP (DD*HHH*WWW)        // 8192
#define TSTRIDE (BB*CC*PP)     // 2097152
#define NWIN 8
#define SSS 1024
#define NHEAD 8
#define HDIM 16
#define THETA 0.7f
#define VTH 1.0f
#define NPERC (TT*BB*PP)       // 65536
#define EPSf 1e-5f

typedef unsigned short ushortT;
typedef unsigned char ucharT;
typedef unsigned int uintT;
typedef _Float16 half_t;
typedef _Float16 f16x8 __attribute__((ext_vector_type(8)));
typedef float    f32x16 __attribute__((ext_vector_type(16)));

typedef const __attribute__((address_space(1))) void* as1_cvp;
typedef __attribute__((address_space(3))) void* as3_vp;

// ---------------- mega-prep: wfrag + w1frags + xsplit in ONE launch ---------
__global__ __launch_bounds__(256) void prep_all(const float* __restrict__ qw,
                                                const float* __restrict__ Wk,
                                                const float* __restrict__ Wp,
                                                const float* __restrict__ x,
                                                half_t* __restrict__ wfrag,
                                                half_t* __restrict__ fragk,
                                                half_t* __restrict__ fragp,
                                                half_t* __restrict__ xsp) {
    int bid = blockIdx.x;
    int tid = threadIdx.x;
    if (bid < 216) {
        int id = bid*256 + tid;              // 55296 = 8*27*4*64
        if (id >= 8*27*4*64) return;
        int lane = id & 63;
        int r = id >> 6;
        int m = r & 3; r >>= 2;
        int t = r % 27;
        int kb = r / 27;
        int o   = m*32 + (lane & 31);
        int ic0 = kb*16 + (lane>>5)*8;
        size_t base = ((size_t)(id>>6))*2*64*8 + (size_t)lane*8;
        #pragma unroll
        for (int j=0;j<8;j++){
            const float* wp = qw + ((size_t)o*CC + ic0 + j)*27;
            float v = wp[t];
            if (t == 13) {                   // t uniform per wave: no divergence
                float kd = 0.f;
                #pragma unroll
                for (int tt=0; tt<9; tt++) kd += wp[tt] + wp[18+tt];
                v -= THETA*kd;
            }
            half_t h = (half_t)v;
            half_t l = (half_t)(v - (float)h);
            wfrag[base + 0*64*8 + j] = h;
            wfrag[base + 1*64*8 + j] = l;
        }
    } else if (bid < 232) {
        int id = (bid-216)*256 + tid;        // 4096
        if (id >= 4096) return;
        const float* W    = (id < 2048) ? Wk : Wp;
        half_t*      frag = (id < 2048) ? fragk : fragp;
        int i2 = id & 2047;
        int lane = i2 & 63;
        int r = i2 >> 6;
        int m = r & 3;
        int kb = r >> 2;
        int o   = m*32 + (lane & 31);
        int ic0 = kb*16 + (lane>>5)*8;
        size_t base = ((size_t)(kb*4+m))*2*64*8 + (size_t)lane*8;
        #pragma unroll
        for (int j=0;j<8;j++){
            float v = W[(size_t)o*CC + ic0 + j];
            half_t h = (half_t)v;
            half_t l = (half_t)(v - (float)h);
            frag[base + 0*64*8 + j] = h;
            frag[base + 1*64*8 + j] = l;
        }
    } else {
        int id = (bid-232)*256 + tid;        // 8*16*8*34*34 = 1,183,744
        if (id >= 8*16*8*34*34) return;
        int wt = id % 34; int r = id/34;
        int hp = r % 34;  r /= 34;
        int dz = r % 8;   r /= 8;
        int icg = r & 15; int tb = r >> 4;
        bool inb = (hp>=1) & (hp<=32) & (wt>=1) & (wt<=32);
        half_t h8[8], l8[8];
        #pragma unroll
        for (int j=0;j<8;j++){
            float v = 0.f;
            if (inb)
                v = x[((size_t)(tb*CC + icg*8+j))*PP + (size_t)dz*1024 + (hp-1)*32 + (wt-1)];
            half_t h = (half_t)v;
            half_t l = (half_t)(v - (float)h);
            h8[j]=h; l8[j]=l;
        }
        #pragma unroll
        for (int sp=0; sp<2; sp++){
            size_t gu = (((((size_t)tb*2 + sp)*16 + icg)*8 + dz)*34 + hp)*34 + wt;
            half_t* dst = xsp + gu*8;
            const half_t* src = (sp==0)?h8:l8;
            #pragma unroll
            for (int j=0;j<8;j++) dst[j] = src[j];
        }
    }
}

// ---------------- conv (full-K) + FUSED k-gemm phase 2 ----------------------
__global__ __launch_bounds__(512,2) void conv_mfma4(const half_t* __restrict__ xsp,
                                                    const half_t* __restrict__ wfrag,
                                                    const half_t* __restrict__ wk,
                                                    float* __restrict__ y,
                                                    float* __restrict__ yk) {
    extern __shared__ half_t slab[];         // 2 x 3264 units x 16B
    int tid  = threadIdx.x;
    int wid  = tid >> 6;
    int lane = tid & 63;
    int ln   = lane & 31;
    int half_ = lane >> 5;
    int hg = blockIdx.x;                     // 0..7
    int dp = blockIdx.y;                     // 0..3
    int tb = blockIdx.z;                     // 0..7
    int H0 = hg*4, d0 = dp*2;
    int r  = wid & 3;                        // h-row within block
    int mh = wid >> 2;                       // m-half: owns m = mh*2 + {0,1}

    auto STAGE = [&](int kb, int bsel) {
        half_t* bufp = slab + (size_t)bsel*(3264*8);
        #pragma unroll 1
        for (int k2=0; k2<7; k2++) {
            int u = tid + (k2<<9);
            if (u < 3264) {
                int sp  = (u >= 1632) ? 1 : 0;
                int r1  = u - sp*1632;
                int icg = (r1 >= 816) ? 1 : 0;
                int p2  = r1 - icg*816;
                int dzs = p2/204; int r3 = p2 - dzs*204;
                int hp  = r3/34;  int wt = r3 - hp*34;
                int dd  = d0 - 1 + dzs;
                const half_t* src = ((unsigned)dd < 8u)
                    ? &xsp[((((((size_t)tb*2 + sp)*16 + (kb*2+icg))*8 + dd)*34 + (H0+hp))*34 + wt)*8]
                    : &xsp[(size_t)ln*8];    // hp=0 halo row of xsp: guaranteed zeros
                __builtin_amdgcn_global_load_lds((as1_cvp)src,
                    (as3_vp)(bufp + (size_t)u*8), 16, 0, 0);
            }
        }
    };

    f32x16 accA[2][2], accB[2][2];           // [dt][mm]; A: kb0-3, B: kb4-7
    #pragma unroll
    for (int dt=0;dt<2;dt++)
        #pragma unroll
        for (int mm=0;mm<2;mm++)
            #pragma unroll
            for (int i=0;i<16;i++){ accA[dt][mm][i]=0.f; accB[dt][mm][i]=0.f; }

    f16x8 ca[2][2];
    #pragma unroll
    for (int mm=0;mm<2;mm++)
        #pragma unroll
        for (int sp=0;sp<2;sp++)
            ca[mm][sp] = *(const f16x8*)&wfrag[((((size_t)0*4 + (mh*2+mm))*2+sp)*64 + lane)*8];

    asm volatile("" ::: "memory");
    STAGE(0,0);
    STAGE(1,1);
    asm volatile("" ::: "memory");

    auto KBODY = [&](int kk, f32x16 (&acc)[2][2]) {
        if (kk == 0) {
            if (wid < 3) asm volatile("s_waitcnt vmcnt(7)" ::: "memory");
            else         asm volatile("s_waitcnt vmcnt(6)" ::: "memory");
        } else {
            asm volatile("s_waitcnt vmcnt(63)" ::: "memory");
        }
        __builtin_amdgcn_s_barrier();        // publish buf[kk&1]
        asm volatile("" ::: "memory");
        const half_t* bufp = slab + (size_t)(kk&1)*(3264*8);

        f16x8 cbC[2][2], cbN[2][2];
        #pragma unroll
        for (int dt=0; dt<2; dt++){
            int unitb = dt*204 + r*34 + ln;
            #pragma unroll
            for (int sp=0; sp<2; sp++)
                cbC[dt][sp] = *(const f16x8*)&bufp[(size_t)((sp*2+half_)*816 + unitb)*8];
        }

        #pragma unroll 1
        for (int t=0; t<27; t++) {
            int t2 = (t<26)? t+1 : 26;
            int dz2=t2/9; int rr2=t2-dz2*9; int dh2=rr2/3; int dw2=rr2-dh2*3;
            #pragma unroll
            for (int dt=0; dt<2; dt++){
                int unitb = (dt + dz2)*204 + (r+dh2)*34 + (ln+dw2);
                #pragma unroll
                for (int sp=0; sp<2; sp++)
                    cbN[dt][sp] = *(const f16x8*)&bufp[(size_t)((sp*2+half_)*816 + unitb)*8];
            }
            f16x8 na[2][2];
            int nt  = (t<26)? t+1 : 0;
            int nkb = (t<26)? kk  : ((kk<7)? kk+1 : kk);
            #pragma unroll
            for (int mm=0;mm<2;mm++)
                #pragma unroll
                for (int sp=0;sp<2;sp++)
                    na[mm][sp] = *(const f16x8*)&wfrag[((((size_t)(nkb*27+nt)*4+(mh*2+mm))*2+sp)*64 + lane)*8];
            #pragma unroll
            for (int dt=0;dt<2;dt++)
                #pragma unroll
                for (int mm=0;mm<2;mm++) acc[dt][mm] = __builtin_amdgcn_mfma_f32_32x32x16_f16(ca[mm][0], cbC[dt][0], acc[dt][mm],0,0,0);
            #pragma unroll
            for (int dt=0;dt<2;dt++)
                #pragma unroll
                for (int mm=0;mm<2;mm++) acc[dt][mm] = __builtin_amdgcn_mfma_f32_32x32x16_f16(ca[mm][0], cbC[dt][1], acc[dt][mm],0,0,0);
            #pragma unroll
            for (int dt=0;dt<2;dt++)
                #pragma unroll
                for (int mm=0;mm<2;mm++) acc[dt][mm] = __builtin_amdgcn_mfma_f32_32x32x16_f16(ca[mm][1], cbC[dt][0], acc[dt][mm],0,0,0);
            #pragma unroll
            for (int dt=0;dt<2;dt++)
                #pragma unroll
                for (int sp=0;sp<2;sp++) cbC[dt][sp] = cbN[dt][sp];
            #pragma unroll
            for (int mm=0;mm<2;mm++)
                #pragma unroll
                for (int sp=0;sp<2;sp++) ca[mm][sp] = na[mm][sp];
        }
        asm volatile("" ::: "memory");
        __builtin_amdgcn_s_barrier();        // all waves done reading buf[kk&1]
        asm volatile("" ::: "memory");
        if (kk < 6) STAGE(kk+2, kk&1);       // refill the buffer just vacated
    };

    #pragma unroll 1
    for (int kk=0; kk<4; kk++) KBODY(kk, accA);
    #pragma unroll 1
    for (int kk=4; kk<8; kk++) KBODY(kk, accB);

    {
        int h = H0 + r;
        #pragma unroll
        for (int dt=0; dt<2; dt++) {
            int d = d0 + dt;
            #pragma unroll
            for (int mm=0; mm<2; mm++) {
                #pragma unroll
                for (int reg=0; reg<16; reg++) {
                    int row = (reg&3) + 8*(reg>>2) + 4*half_;
                    int o = (mh*2+mm)*32 + row;
                    y[((size_t)tb*CC + o)*PP + d*1024 + h*32 + ln]
                        = accA[dt][mm][reg] + accB[dt][mm][reg];
                }
            }
        }
    }

    // ---- phase 2: k-gemm for this block's (d0..d0+1, H0..H0+3, tb) --------
    {
        int d = d0 + (wid >> 2);
        int h = H0 + (wid & 3);
        f32x16 kacc[4];
        #pragma unroll
        for (int m=0;m<4;m++)
            #pragma unroll
            for (int i=0;i<16;i++) kacc[m][i] = 0.f;

        #pragma unroll 2
        for (int kb=0; kb<8; kb++) {
            f16x8 b[2];
            #pragma unroll
            for (int sp=0; sp<2; sp++) {
                size_t gu = (((((size_t)tb*2 + sp)*16 + (kb*2+half_))*8 + d)*34 + (h+1))*34 + (ln+1);
                b[sp] = *(const f16x8*)&xsp[gu*8];
            }
            #pragma unroll
            for (int m=0; m<4; m++) {
                const half_t* wb = wk + ((size_t)(kb*4+m))*2*64*8 + (size_t)lane*8;
                f16x8 a0 = *(const f16x8*)&wb[0*64*8];
                f16x8 a1 = *(const f16x8*)&wb[1*64*8];
                kacc[m] = __builtin_amdgcn_mfma_f32_32x32x16_f16(a0, b[0], kacc[m],0,0,0);
                kacc[m] = __builtin_amdgcn_mfma_f32_32x32x16_f16(a0, b[1], kacc[m],0,0,0);
                kacc[m] = __builtin_amdgcn_mfma_f32_32x32x16_f16(a1, b[0], kacc[m],0,0,0);
            }
        }
        #pragma unroll
        for (int m=0; m<4; m++) {
            #pragma unroll
            for (int reg=0; reg<16; reg++) {
                int row = (reg&3) + 8*(reg>>2) + 4*half_;
                int o = m*32 + row;
                yk[((size_t)tb*CC + o)*PP + d*1024 + h*32 + ln] = kacc[m][reg];
            }
        }
    }
}

// ---------------- p-gemm via f16 MFMA (plain: no stats epilogue) ------------
__global__ __launch_bounds__(256) void pgemm_mfma(const ushortT* __restrict__ spkb,
                                                  const half_t* __restrict__ wp,
                                                  float* __restrict__ y) {
    int tid  = threadIdx.x;
    int wid  = tid >> 6;
    int lane = tid & 63;
    int ln   = lane & 31;
    int half_ = lane >> 5;
    int hg = blockIdx.x, d = blockIdx.y, tb = blockIdx.z;
    int h = hg*4 + wid;
    int p = d*1024 + h*32 + ln;

    f32x16 acc[4];
    #pragma unroll
    for (int m=0;m<4;m++)
        #pragma unroll
        for (int i=0;i<16;i++) acc[m][i] = 0.f;

    #pragma unroll 2
    for (int kb=0; kb<8; kb++) {
        f16x8 b = *(const f16x8*)&spkb[(((size_t)tb*16 + (kb*2+half_))*PP + p)*8];
        #pragma unroll
        for (int m=0; m<4; m++) {
            const half_t* wb = wp + ((size_t)(kb*4+m))*2*64*8 + (size_t)lane*8;
            f16x8 a0 = *(const f16x8*)&wb[0*64*8];
            f16x8 a1 = *(const f16x8*)&wb[1*64*8];
            acc[m] = __builtin_amdgcn_mfma_f32_32x32x16_f16(a0, b, acc[m],0,0,0);
            acc[m] = __builtin_amdgcn_mfma_f32_32x32x16_f16(a1, b, acc[m],0,0,0);
        }
    }
    #pragma unroll
    for (int m=0; m<4; m++) {
        #pragma unroll
        for (int reg=0; reg<16; reg++) {
            int row = (reg&3) + 8*(reg>>2) + 4*half_;
            int o = m*32 + row;
            y[((size_t)tb*CC + o)*PP + p] = acc[m][reg];
        }
    }
}

// ---------------- per-(src,b,win,c) sum & sumsq partials ---------------------
__global__ __launch_bounds__(128) void win_stats(const float* __restrict__ q,
        const float* __restrict__ k, const float* __restrict__ x,
        float* __restrict__ rsum, float* __restrict__ rsq) {
    int blk = blockIdx.x;
    int src = blk >> 11;
    int r   = blk & 2047;
    const float* base = (src==0) ? q : ((src==1) ? k : x);
    int c  = r & 127;
    int wi = (r >> 7) & 7;
    int b  = r >> 10;
    int wd = wi>>2, wh = (wi>>1)&1, ww = wi&1;
    int tid = threadIdx.x;
    float s=0.f, s2=0.f;
    for (int t=0;t<TT;t++){
        const float* p = base + ((size_t)(t*BB+b)*CC + c)*PP;
        for (int si=tid; si<SSS; si+=128){
            int ld = si>>8, lh=(si>>4)&15, lw=si&15;
            float v = p[((wd*4+ld)<<10) + ((wh*16+lh)<<5) + (ww*16+lw)];
            s += v; s2 += v*v;
        }
    }
    __shared__ float ls[128], ls2[128];
    ls[tid]=s; ls2[tid]=s2; __syncthreads();
    for (int off=64;off>0;off>>=1){
        if(tid<off){ ls[tid]+=ls[tid+off]; ls2[tid]+=ls2[tid+off]; }
        __syncthreads();
    }
    if (tid==0){ rsum[blk]=ls[0]; rsq[blk]=ls2[0]; }
}

// ---------------- finalize stats + routing + top-4 in ONE block --------------
__global__ __launch_bounds__(384) void route_fin(const float* __restrict__ rsum,
        const float* __restrict__ rsq,
        const float* __restrict__ qg, const float* __restrict__ qb,
        const float* __restrict__ kg, const float* __restrict__ kb,
        float* __restrict__ stats, int* __restrict__ idxout) {
    __shared__ float qn[16*128], kn[16*128], ar[16*8];
    __shared__ float csum[384], csq[384];
    int tid = threadIdx.x;
    {
        int src = tid >> 7, c = tid & 127;
        float s=0.f, s2=0.f;
        for (int bw=0; bw<16; bw++){
            int idx = src*2048 + bw*128 + c;
            s  += rsum[idx];
            s2 += rsq[idx];
        }
        stats[src*256 + c]       = s;
        stats[src*256 + 128 + c] = s2;
        csum[tid]=s; csq[tid]=s2;
    }
    __syncthreads();
    for (int e=tid; e<16*128; e+=384){
        int c = e&127;
        float qm = csum[c]*(1.f/NPERC);
        float qv = csq[c]*(1.f/NPERC) - qm*qm;
        float qr = rsqrtf(qv + EPSf);
        qn[e] = (rsum[e]*(1.f/(TT*SSS)) - qm)*qr*qg[c] + qb[c];
        float km = csum[128+c]*(1.f/NPERC);
        float kv = csq[128+c]*(1.f/NPERC) - km*km;
        float kr = rsqrtf(kv + EPSf);
        kn[e] = (rsum[2048+e]*(1.f/(TT*SSS)) - km)*kr*kg[c] + kb[c];
    }
    __syncthreads();
    if (tid < 128){
        int b = tid>>6, w=(tid>>3)&7, v=tid&7;
        float s=0.f;
        for (int c=0;c<128;c++) s += qn[(b*8+w)*128+c]*kn[(b*8+v)*128+c];
        ar[(b*8+w)*8+v] = s * 0.25f;
    }
    __syncthreads();
    if (tid < 16){
        const float* row = &ar[tid*8];
        bool used[8] = {false,false,false,false,false,false,false,false};
        for (int j=0;j<4;j++){
            int best=0; float bv=-3.0e38f;
            for (int v=0; v<8; v++){
                if (!used[v] && row[v] > bv){ bv=row[v]; best=v; }
            }
            used[best]=true;
            idxout[tid*4+j]=best;
        }
    }
}

// ---------------- LIF+BN for q,k,v in ONE launch (grid.y = src) -------------
__global__ __launch_bounds__(256) void lif_bn_win3(const float* __restrict__ qin,
        const float* __restrict__ kin, const float* __restrict__ xin,
        ucharT* __restrict__ qs, ucharT* __restrict__ ks, ucharT* __restrict__ vs,
        const float* __restrict__ stats,
        const float* __restrict__ qg, const float* __restrict__ qb,
        const float* __restrict__ kg, const float* __restrict__ kb,
        const float* __restrict__ vg, const float* __restrict__ vb) {
    int src = blockIdx.y;
    const float* in  = (src==0) ? qin : ((src==1) ? kin : xin);
    ucharT*      spk = (src==0) ? qs  : ((src==1) ? ks  : vs);
    const float* gamma = (src==0) ? qg : ((src==1) ? kg : vg);
    const float* beta  = (src==0) ? qb : ((src==1) ? kb : vb);
    int e4 = blockIdx.x*256 + threadIdx.x;
    if (e4 >= BB*CC*PP/4) return;
    int e = e4*4;
    int p = e & (PP-1);
    int c = (e >> 13) & 127;
    int b = e >> 20;
    float mean = stats[src*256 + c]*(1.f/NPERC);
    float var  = stats[src*256 + 128 + c]*(1.f/NPERC) - mean*mean;
    float sc = rsqrtf(var+EPSf)*gamma[c];
    float sh = beta[c] - mean*sc;
    int d = p>>10, h=(p>>5)&31, w=p&31;     // w multiple of 4: same window/si-block
    int wi = ((d>>2)*2 + (h>>4))*2 + (w>>4);
    int si = (((d&3)<<4) + (h&15))*16 + (w&15);
    size_t widx = ((size_t)(b*NWIN+wi)*CC + c)*SSS + si;   // multiple of 4
    float v[4] = {0.f,0.f,0.f,0.f};
    #pragma unroll
    for (int t=0;t<TT;t++){
        float4 raw = *(const float4*)&in[(size_t)t*TSTRIDE + e];
        float xs[4] = {raw.x, raw.y, raw.z, raw.w};
        uintT pack = 0;
        #pragma unroll
        for (int i=0;i<4;i++){
            float xn = xs[i]*sc + sh;
            v[i] = (v[i]+xn)*0.5f;
            float s = (v[i]>=VTH)?1.f:0.f;
            pack |= (v[i]>=VTH ? 1u : 0u) << (8*i);
            v[i] *= (1.f - s);
        }
        *(uintT*)&spk[(size_t)t*TSTRIDE + widx] = pack;
    }
}

// ---------------- window attention + output LIF -> f16 spike frags ----------
__global__ __launch_bounds__(256) void attn_lif(const ucharT* __restrict__ qspk,
        const ucharT* __restrict__ kspk, const ucharT* __restrict__ vspk,
        const int* __restrict__ idx, ushortT* __restrict__ spkb) {
    int id = blockIdx.x*256 + threadIdx.x;   // [b2][wi8][hh8][s4 256][ddq4] = 131072
    int ddq = id & 3;                        // dd = ddq*4 .. +3
    int s4  = (id>>2) & 255;                 // s = s4*4 .. +3
    int hh  = (id>>10) & 7;
    int wi  = (id>>13) & 7;
    int b   = id>>16;
    int bw  = b*NWIN+wi;
    int s0  = s4*4;
    int dd0 = ddq*4;
    size_t qbase = ((size_t)bw*CC + hh*HDIM + dd0)*SSS + s0;
    size_t sbase[4];
    #pragma unroll
    for (int j=0;j<4;j++){
        int srcw = idx[bw*4+j];
        sbase[j] = ((size_t)(b*NWIN+srcw)*CC + hh*HDIM + dd0)*SSS + s0;
    }
    int wd = wi>>2, wh = (wi>>1)&1, ww = wi&1;
    int d3 = wd*4 + (s0>>8), h3 = wh*16 + ((s0>>4)&15), w3 = ww*16 + (s0&15);
    int p0 = (d3<<10) + (h3<<5) + w3;        // p for si: p0+si (same d3/h3)
    int icg  = hh*2 + (ddq>>1);
    int slot = (ddq&1)*4;

    float v[4] = {0.f,0.f,0.f,0.f};
    float v2[4][4];
    #pragma unroll
    for (int i=0;i<4;i++)
        #pragma unroll
        for (int si=0;si<4;si++) v2[i][si]=0.f;

    #pragma unroll 1
    for (int t=0;t<TT;t++){
        size_t toff = (size_t)t*TSTRIDE;
        uintT km[4] = {0,0,0,0}, vm[4] = {0,0,0,0};
        #pragma unroll
        for (int j=0;j<4;j++){
            const ucharT* kp = kspk+toff+sbase[j];
            const ucharT* vp = vspk+toff+sbase[j];
            #pragma unroll
            for (int i=0; i<4; i++){
                km[i] += *(const uintT*)&kp[(size_t)i*SSS];   // bytes <= 4: no carry
                vm[i] += *(const uintT*)&vp[(size_t)i*SSS];
            }
        }
        const ucharT* qp = qspk+toff+qbase;
        uintT atti = 0;                      // per-byte dot over this dd-quarter
        #pragma unroll
        for (int i=0;i<4;i++){
            uintT q4 = *(const uintT*)&qp[(size_t)i*SSS];     // bytes in {0,1}
            uintT tq = (q4 + 0x7F7F7F7Fu) & 0x80808080u;      // 0x80 where q=1
            uintT mask = tq - (tq >> 7);                      // 0x7F where q=1
            atti += km[i] & mask;            // km bytes <=4 -> fits in 0x7F
        }
        atti += (uintT)__shfl_xor((int)atti, 1);              // quad sum over dd
        atti += (uintT)__shfl_xor((int)atti, 2);              // bytes <=64: exact
        int tb2 = t*BB + b;
        size_t obase = (((size_t)tb2*16 + icg)*PP + p0)*8 + slot;
        #pragma unroll
        for (int si=0; si<4; si++){
            float att = (float)((atti >> (8*si)) & 255u) * 0.25f;
            v[si] = (v[si]+att)*0.5f;
            float sp = (v[si]>=VTH)?1.f:0.f;
            v[si] *= (1.f-sp);
            float spq = sp*0.25f;
            uintT lo=0, hi=0;
            #pragma unroll
            for (int i=0;i<4;i++){
                float ov = spq*(float)((vm[i] >> (8*si)) & 255u);
                v2[i][si] = (v2[i][si]+ov)*0.5f;
                float s2 = (v2[i][si]>=VTH)?1.f:0.f;
                v2[i][si] *= (1.f-s2);
                uintT bs = (s2 != 0.f) ? 0x3C00u : 0u;        // f16 1.0
                if (i<2) lo |= bs << (16*i); else hi |= bs << (16*(i-2));
            }
            uint2 pk; pk.x = lo; pk.y = hi;
            *(uint2*)&spkb[obase + (size_t)si*8] = pk;        // 8B store
        }
    }
}

// ---------------- p-stats: partials over (tb,c) ------------------------------
__global__ __launch_bounds__(256) void pstats_part(const float* __restrict__ xin,
        float* __restrict__ part_sum, float* __restrict__ part_sq) {
    int blk = blockIdx.x;                    // tb*128 + c
    int c = blk & 127, tb = blk >> 7;
    int tid = threadIdx.x;
    const float* p = xin + ((size_t)tb*CC + c)*PP;
    float s=0.f, s2=0.f;
    for (int i=tid; i<PP; i+=256){ float v=p[i]; s+=v; s2+=v*v; }
    __shared__ float ls[256], ls2[256];
    ls[tid]=s; ls2[tid]=s2; __syncthreads();
    for (int off=128; off>0; off>>=1){
        if (tid<off){ ls[tid]+=ls[tid+off]; ls2[tid]+=ls2[tid+off]; }
        __syncthreads();
    }
    if (tid==0){ part_sum[blk]=ls[0]; part_sq[blk]=ls2[0]; }
}

// ---------------- final BN apply (folds the 8-partial finalize; float4) -----
__global__ __launch_bounds__(256) void bn_apply(const float* __restrict__ xin,
        float* __restrict__ yout,
        const float* __restrict__ part_sum, const float* __restrict__ part_sq,
        const float* __restrict__ gamma, const float* __restrict__ beta) {
    size_t i4 = (size_t)blockIdx.x*256 + threadIdx.x;
    if (i4 >= (size_t)TT*BB*CC*PP/4) return;
    size_t i = i4*4;
    int c = (int)((i>>13)&127);
    float s=0.f, s2=0.f;
    #pragma unroll
    for (int tb=0; tb<8; tb++){
        s  += part_sum[tb*128+c];
        s2 += part_sq[tb*128+c];
    }
    float mean = s*(1.f/NPERC);
    float var  = s2*(1.f/NPERC) - mean*mean;
    float sc = rsqrtf(var+EPSf)*gamma[c];
    float sh = beta[c] - mean*sc;
    float4 a = *(const float4*)&xin[i];
    a.x = a.x*sc + sh;
    a.y = a.y*sc + sh;
    a.z = a.z*sc + sh;
    a.w = a.w*sc + sh;
    *(float4*)&yout[i] = a;
}

extern "C" void kernel_launch(void* const* d_in, const int* in_sizes, int n_in,
                              void* d_out, int out_size, void* d_ws, size_t ws_size,
                              hipStream_t stream) {
    const float* x  = (const float*)d_in[0];
    const float* qw = (const float*)d_in[1];
    const float* qg = (const float*)d_in[2];
    const float* qb = (const float*)d_in[3];
    const float* kw = (const float*)d_in[4];
    const float* kg = (const float*)d_in[5];
    const float* kb = (const float*)d_in[6];
    const float* vg = (const float*)d_in[7];
    const float* vb = (const float*)d_in[8];
    const float* pw = (const float*)d_in[9];
    const float* pg = (const float*)d_in[10];
    const float* pb = (const float*)d_in[11];
    float* out = (float*)d_out;
    float* ws  = (float*)d_ws;

    const size_t NEL = (size_t)TT*TSTRIDE;   // 8,388,608 floats
    // ---- workspace layout (R12 best) ----------------------------------------
    float* qconv = ws;
    half_t* xsp  = (half_t*)(ws + 2*NEL);
    const size_t KCONV_OFF = 2*NEL + 10747904;        // past xsp end (2NEL+9469952)
    float* kconv = ws + KCONV_OFF;
    float* wf_base = ws + KCONV_OFF + NEL;            // weight area
    half_t* wfrag  = (half_t*)wf_base;                // 884736 halves (442368 f)
    half_t* wkfrag = (half_t*)(wf_base + 442368);     // 32768 halves (16384 f)
    half_t* wpfrag = (half_t*)(wf_base + 442368 + 16384 + 442368); // 32768 halves
    float* stats = ws + 5*NEL;
    float* rsum = stats + 1024;              // 6144
    float* rsq  = rsum + 6144;               // 6144
    float* ppart_sum = rsq + 6144;           // 1024
    float* ppart_sq  = ppart_sum + 1024;     // 1024
    int*   idxp = (int*)(ppart_sq + 1024);   // 64 ints

    ucharT* qspk = (ucharT*)(ws + 2*NEL);             // after xsp dead
    ucharT* kspk = (ucharT*)(ws + 2*NEL) + 8388608;
    ucharT* vspk = (ucharT*)(ws + 2*NEL) + 16777216;
    ushortT* spkb  = (ushortT*)ws;                    // qconv dead after lif
    float*  pconv  = ws + KCONV_OFF;                  // kconv dead after lif

    prep_all<<<4856,256,0,stream>>>(qw, kw, pw, x, wfrag, wkfrag, wpfrag, xsp);
    {
        // 104,448 B dynamic LDS (> 64 KB): opt in once (host-side, capture-safe)
        static bool attr_set = false;
        const int shmem = 2*3264*8*(int)sizeof(half_t);
        if (!attr_set) {
            hipFuncSetAttribute((const void*)conv_mfma4,
                                hipFuncAttributeMaxDynamicSharedMemorySize, shmem);
            attr_set = true;
        }
        dim3 cg(8,4,8);
        conv_mfma4<<<cg,512,shmem,stream>>>(xsp, wfrag, wkfrag, qconv, kconv);
    }
    win_stats<<<6144,128,0,stream>>>(qconv, kconv, x, rsum, rsq);
    route_fin<<<1,384,0,stream>>>(rsum, rsq, qg,qb,kg,kb, stats, idxp);
    {
        dim3 lg(2048,3);
        lif_bn_win3<<<lg,256,0,stream>>>(qconv,kconv,x,
                                         qspk,kspk,vspk,
                                         stats, qg,qb,kg,kb,vg,vb);
    }
    attn_lif<<<512,256,0,stream>>>(qspk,kspk,vspk,idxp,spkb);
    {
        dim3 gg(8,8,8);
        pgemm_mfma<<<gg,256,0,stream>>>(spkb, wpfrag, pconv);
    }
    pstats_part<<<1024,256,0,stream>>>(pconv, ppart_sum, ppart_sq);
    bn_apply<<<8192,256,0,stream>>>(pconv, out, ppart_sum, ppart_sq, pg, pb);
}